// Round 5
// baseline (212.265 us; speedup 1.0000x reference)
//
#include <hip/hip_runtime.h>
#include <math.h>

#define Bb 8
#define Cc 128
#define Nn 3136                  // 56*56 real spatial
#define Np 3200                  // padded spatial (50 x 64)
#define NT 50                    // 64-row tiles per batch
#define Mm (Bb*Cc*Nn)            // elements per output tensor
#define PADV 72                  // s_pt row stride (u16): 144 B (9x16B)
#define L2E 1.44269504088896340736f
#define C44 (44.0f * L2E)        // shift 44 in log2 domain

// xt2: [b][T(50)][seg(16)][row(64)][8 u16]   seg = channel-chunk of 8
#define XT2B (NT*16*64*8)        // 409600 u16 per batch
// xc2: [b][T(50)][seg(8)][c(128)][8 u16]     seg = i-chunk of 8
#define XC2B (NT*8*128*8)        // 409600 u16 per batch

typedef unsigned short u16;
typedef unsigned int   u32;
typedef __attribute__((ext_vector_type(8)))  u16      u16x8;
typedef __attribute__((ext_vector_type(8)))  _Float16 f16x8;
typedef __attribute__((ext_vector_type(4)))  _Float16 f16x4;
typedef __attribute__((ext_vector_type(4)))  float    f32x4;
typedef __attribute__((ext_vector_type(16))) float    f32x16;

__device__ __forceinline__ float exp2fast(float x) {
#if __has_builtin(__builtin_amdgcn_exp2f)
    return __builtin_amdgcn_exp2f(x);
#else
    float r; asm("v_exp_f32 %0, %1" : "=v"(r) : "v"(x)); return r;
#endif
}

// ---------------------------------------------------------------------------
// Prep: x f32 -> fragment-major fp16 tiles xt2/xc2 (all later MFMA fragment
// loads are perfectly coalesced global loads). Slot3 = gamma; x-copy done in
// finish_kernel. grid 400 = 8 b * 50 n-blocks; nblk 49 zero-pads tile 49.
// ---------------------------------------------------------------------------
__global__ __launch_bounds__(256) void prep_kernel(const float* __restrict__ x,
                                                   const float* __restrict__ gamma_p,
                                                   float* __restrict__ out,
                                                   u16* __restrict__ xt2,
                                                   u16* __restrict__ xc2,
                                                   float* __restrict__ row_d) {
    const int bx = blockIdx.x;
    const int b = bx / 50, nblk = bx % 50;
    const int t = threadIdx.x;

    if (nblk == 49) {            // pad tile: rows 3136..3199 all zero
        const u16x8 z8 = {0, 0, 0, 0, 0, 0, 0, 0};
        u16* dt = xt2 + ((size_t)b * NT + 49) * (16 * 64 * 8);
        u16* dc = xc2 + ((size_t)b * NT + 49) * (8 * 128 * 8);
        #pragma unroll
        for (int it = 0; it < 4; ++it) {
            *(u16x8*)&dt[(it * 256 + t) * 8] = z8;
            *(u16x8*)&dc[(it * 256 + t) * 8] = z8;
        }
        if (t < 64) row_d[b * Np + Nn + t] = 1.0f;   // pad denominators: 1
        return;
    }

    __shared__ float lx[Cc][65];
    const int n0 = nblk * 64;

    // phase 1: coalesced read
    #pragma unroll 8
    for (int r = 0; r < 32; ++r) {
        const int c = r * 4 + (t >> 6);
        const int g = (b * Cc + c) * Nn + n0 + (t & 63);
        lx[c][t & 63] = x[g];
    }
    __syncthreads();

    // phase 2: xt2 — thread (row nl, cseg) -> segs cseg*4+k, fully coalesced
    {
        const int nl = t & 63, cseg = t >> 6;
        u16x8 hv[4];
        #pragma unroll
        for (int cc = 0; cc < 32; ++cc) {
            const _Float16 hh = (_Float16)lx[cseg * 32 + cc][nl];
            hv[cc >> 3][cc & 7] = __builtin_bit_cast(u16, hh);
        }
        u16* base = xt2 + (((size_t)(b * NT + nblk) * 16 + cseg * 4) * 64 + nl) * 8;
        #pragma unroll
        for (int k = 0; k < 4; ++k) *(u16x8*)&base[k * (64 * 8)] = hv[k];
    }
    // phase 2b: xc2 — thread (c, half) -> segs half*4+k
    {
        const int c = t >> 1, half = t & 1;
        u16x8 hv[4];
        #pragma unroll
        for (int k = 0; k < 32; ++k) {
            const _Float16 hh = (_Float16)lx[c][half * 32 + k];
            hv[k >> 3][k & 7] = __builtin_bit_cast(u16, hh);
        }
        u16* base = xc2 + (((size_t)(b * NT + nblk) * 8 + half * 4) * 128 + c) * 8;
        #pragma unroll
        for (int k = 0; k < 4; ++k) *(u16x8*)&base[k * (128 * 8)] = hv[k];
    }
    if (bx == 0 && t == 0) out[(size_t)3 * Mm] = gamma_p[0];
}

// ---------------------------------------------------------------------------
// Stats: row_d[b,i] += sum_j exp(e_ij - 44). No LDS, no barriers, low-VGPR
// streamed A-loads, dual MFMA chains with CORRECT seg pairing:
// MFMA #kk' uses A-seg (2kk'+h) with Bf[kk'] (loaded from seg 2kk'+h) —
// both wave halves of one MFMA supply the same K=16 slice (k = h*8+e).
// Chain-a: kk'=2kk (seg 4kk+h); chain-b: kk'=2kk+1 (seg 4kk+2+h).
// grid 3136 = 49 i-blocks * 8 j-chunks * 8 b -> 12.25 blocks/CU; (256,5).
// ---------------------------------------------------------------------------
__global__ __launch_bounds__(256, 5) void stats_kernel(const u16* __restrict__ xt2,
                                                       float* __restrict__ row_d) {
    const int bx = blockIdx.x;
    const int b = bx & 7, rem = bx >> 3;
    const int i0t = rem >> 3, jq = rem & 7;      // i-tile 0..48, j-chunk 0..7
    const int t = threadIdx.x;
    const int w = t >> 6, l = t & 63, lane = l & 31, h = l >> 5;
    const int igrp = w & 1, jsub = w >> 1;
    const u16* __restrict__ xb = xt2 + (size_t)b * XT2B;

    f16x8 Bf[8];                                 // resident i-row frags, seg 2kk+h
    const int irow = igrp * 32 + lane;
    #pragma unroll
    for (int kk = 0; kk < 8; ++kk)
        Bf[kk] = *(const f16x8*)&xb[(((size_t)i0t * 16 + 2 * kk + h) * 64 + irow) * 8];

    const int jt0 = jq * 6 + (jq < 2 ? jq : 2);  // 0,7,14,20,26,32,38,44
    const int jcnt = 6 + (jq < 2 ? 1 : 0);       // 7,7,6,6,6,6,6,6
    const int jrow = jsub * 32 + lane;

    float sa = 0.f, sb = 0.f;
    for (int jt = jt0; jt < jt0 + jcnt; ++jt) {
        const u16* ab = &xb[((size_t)jt * 16 * 64 + jrow) * 8];
        f32x16 ea, eb;
        #pragma unroll
        for (int r = 0; r < 16; ++r) { ea[r] = 0.f; eb[r] = 0.f; }
        __builtin_amdgcn_s_setprio(1);
        #pragma unroll
        for (int kk = 0; kk < 4; ++kk) {
            const f16x8 A0 = *(const f16x8*)&ab[(4 * kk + h) * 512];
            const f16x8 A1 = *(const f16x8*)&ab[(4 * kk + 2 + h) * 512];
            ea = __builtin_amdgcn_mfma_f32_32x32x16_f16(A0, Bf[2 * kk],     ea, 0, 0, 0);
            eb = __builtin_amdgcn_mfma_f32_32x32x16_f16(A1, Bf[2 * kk + 1], eb, 0, 0, 0);
        }
        __builtin_amdgcn_s_setprio(0);

        if (jt == i0t) {                          // diagonal tile: masked path
            const bool dsub = (jsub == igrp);
            #pragma unroll
            for (int r = 0; r < 16; ++r) {
                const int mrow = (r & 3) + 8 * (r >> 2) + 4 * h;
                float v = ea[r] + eb[r];
                if (dsub && mrow == lane) v = 0.f;
                const float e = exp2fast(fmaf(v, L2E, -C44));
                if (r & 1) sb += e; else sa += e;
            }
        } else {
            #pragma unroll
            for (int r = 0; r < 16; ++r) {
                const float e = exp2fast(fmaf(ea[r] + eb[r], L2E, -C44));
                if (r & 1) sb += e; else sa += e;
            }
        }
    }
    float ssum = sa + sb;
    ssum += __shfl_xor(ssum, 32, 64);   // combine h-halves (disjoint j-rows)
    if (h == 0) atomicAdd(&row_d[b * Np + i0t * 64 + igrp * 32 + lane], ssum);
}

// ---------------------------------------------------------------------------
// Conv: row_d -> c_i = 44*log2e + log2(d_i), so P = exp2(e*log2e - c_i).
// ---------------------------------------------------------------------------
__global__ __launch_bounds__(256) void conv_kernel(float* __restrict__ row_d) {
    const int i = blockIdx.x * 256 + threadIdx.x;
    row_d[i] = C44 + __log2f(row_d[i]);
}

// ---------------------------------------------------------------------------
// Out (R2 skeleton + 3-way i-split): partial_q[c][j] = sum_{i third q}
// V[c][i] * exp2(e*l2e - c_i). LDS = P^T dbuf only (18432 B), 1 barrier/iter,
// streamed low-VGPR loads, dual energy chains (correct seg pairing as in
// stats). grid 1176 = 8 b * 49 j * 3 q -> 4.6 blocks/CU; (256,4).
// Partials -> slots 0/1/2; finish_kernel combines.
// ---------------------------------------------------------------------------
__global__ __launch_bounds__(256, 4) void out_kernel(const u16* __restrict__ xt2,
                                                     const u16* __restrict__ xc2,
                                                     const float* __restrict__ row_c,
                                                     float* __restrict__ out) {
    __shared__ u16 s_pt[2][64 * PADV];           // P^T dbuf, 2 x 9216 B

    const int bx = blockIdx.x;
    const int b = bx & 7, rem = bx >> 3;         // rem 0..146
    const int j0t = rem / 3, q = rem % 3;        // j-tile 0..48, i-third
    const int ti0 = q * 17;
    const int ti1 = (q == 2) ? 50 : ti0 + 17;    // 17/17/16 tiles
    const int t = threadIdx.x;
    const int w = t >> 6, l = t & 63, lane = l & 31, h = l >> 5;
    const int isub = w & 1, jgrp = w >> 1;       // energy roles
    const int jg = w & 1,  cp = w >> 1;          // PV roles
    const u16* __restrict__ xtb = xt2 + (size_t)b * XT2B;
    const u16* __restrict__ xcb = xc2 + (size_t)b * XC2B;

    f16x8 Bj[8];                                 // resident j-row frags, seg 2kk+h
    const int jrow = jgrp * 32 + lane;
    #pragma unroll
    for (int kk = 0; kk < 8; ++kk)
        Bj[kk] = *(const f16x8*)&xtb[(((size_t)j0t * 16 + 2 * kk + h) * 64 + jrow) * 8];

    f32x16 oa, ob;
    #pragma unroll
    for (int r = 0; r < 16; ++r) { oa[r] = 0.f; ob[r] = 0.f; }

    const int arow = isub * 32 + lane;
    const int ptbase = (jgrp * 32 + lane) * PADV + isub * 32;
    const int pbrow = (jg * 32 + lane) * PADV + h * 8;

    for (int ti = ti0; ti < ti1; ++ti) {
        // energy: dual-chain MFMA, A-frags streamed from L2 (seg-paired)
        f32x16 ea, eb;
        #pragma unroll
        for (int r = 0; r < 16; ++r) { ea[r] = 0.f; eb[r] = 0.f; }
        const u16* ab = &xtb[((size_t)ti * 16 * 64 + arow) * 8];
        __builtin_amdgcn_s_setprio(1);
        #pragma unroll
        for (int kk = 0; kk < 4; ++kk) {
            const f16x8 A0 = *(const f16x8*)&ab[(4 * kk + h) * 512];
            const f16x8 A1 = *(const f16x8*)&ab[(4 * kk + 2 + h) * 512];
            ea = __builtin_amdgcn_mfma_f32_32x32x16_f16(A0, Bj[2 * kk],     ea, 0, 0, 0);
            eb = __builtin_amdgcn_mfma_f32_32x32x16_f16(A1, Bj[2 * kk + 1], eb, 0, 0, 0);
        }
        __builtin_amdgcn_s_setprio(0);

        // P = exp2(e*l2e - c_i) -> s_pt[ti&1]; diag branch hoisted
        u16* pt = &s_pt[ti & 1][0];
        const float* cbase = &row_c[b * Np + ti * 64 + isub * 32];
        if (ti == j0t) {
            const bool dsub = (isub == jgrp);
            #pragma unroll
            for (int qq = 0; qq < 4; ++qq) {
                const f32x4 cv = *(const f32x4*)&cbase[qq * 8 + h * 4];
                f16x4 pv;
                #pragma unroll
                for (int r = 0; r < 4; ++r) {
                    const int m = qq * 8 + h * 4 + r;
                    float v = ea[qq * 4 + r] + eb[qq * 4 + r];
                    if (dsub && m == lane) v = 0.f;
                    pv[r] = (_Float16)exp2fast(fmaf(v, L2E, -cv[r]));
                }
                *(f16x4*)&pt[ptbase + qq * 8 + h * 4] = pv;
            }
        } else {
            #pragma unroll
            for (int qq = 0; qq < 4; ++qq) {
                const f32x4 cv = *(const f32x4*)&cbase[qq * 8 + h * 4];
                f16x4 pv;
                #pragma unroll
                for (int r = 0; r < 4; ++r)
                    pv[r] = (_Float16)exp2fast(
                        fmaf(ea[qq * 4 + r] + eb[qq * 4 + r], L2E, -cv[r]));
                *(f16x4*)&pt[ptbase + qq * 8 + h * 4] = pv;
            }
        }
        __syncthreads();                         // s_pt[ti&1] complete

        // PV: V-frags streamed from L2; Bp from s_pt (identical to R2 proven)
        const u16* vb = &xcb[((size_t)ti * 8 * 128 + cp * 64 + lane) * 8];
        __builtin_amdgcn_s_setprio(1);
        #pragma unroll
        for (int kk = 0; kk < 4; ++kk) {
            const f16x8 Bp  = *(const f16x8*)&pt[pbrow + kk * 16];
            const f16x8 Av0 = *(const f16x8*)&vb[((2 * kk + h) * 128) * 8];
            const f16x8 Av1 = *(const f16x8*)&vb[((2 * kk + h) * 128 + 32) * 8];
            oa = __builtin_amdgcn_mfma_f32_32x32x16_f16(Av0, Bp, oa, 0, 0, 0);
            ob = __builtin_amdgcn_mfma_f32_32x32x16_f16(Av1, Bp, ob, 0, 0, 0);
        }
        __builtin_amdgcn_s_setprio(0);
    }

    // epilogue: raw f32 partials -> out slot q (scratch until finish_kernel)
    #pragma unroll
    for (int r = 0; r < 16; ++r) {
        const int mrow = (r & 3) + 8 * (r >> 2) + 4 * h;
        const int jj = j0t * 64 + jg * 32 + lane;
        {
            const int c = cp * 64 + mrow;
            const size_t pos = (size_t)(b * Cc + c) * Nn + jj;
            out[(size_t)q * Mm + pos] = oa[r];
        }
        {
            const int c = cp * 64 + 32 + mrow;
            const size_t pos = (size_t)(b * Cc + c) * Nn + jj;
            out[(size_t)q * Mm + pos] = ob[r];
        }
    }
}

// ---------------------------------------------------------------------------
// Finish: o = relu(p0+p1+p2); slot0 = gamma*o + x; slot1 = o; slot2 = x.
// Pure streaming: 51.4 MB read + 38.6 MB write.
// ---------------------------------------------------------------------------
__global__ __launch_bounds__(256) void finish_kernel(const float* __restrict__ x,
                                                     const float* __restrict__ gamma_p,
                                                     float* __restrict__ out) {
    const float gamma = gamma_p[0];
    const size_t base = ((size_t)blockIdx.x * 256 + threadIdx.x) * 4;
    const f32x4 pa = *(const f32x4*)&out[base];
    const f32x4 pb = *(const f32x4*)&out[(size_t)Mm + base];
    const f32x4 pc = *(const f32x4*)&out[(size_t)2 * Mm + base];
    const f32x4 xv = *(const f32x4*)&x[base];
    f32x4 yo, oo;
    #pragma unroll
    for (int r = 0; r < 4; ++r) {
        const float o = fmaxf(pa[r] + pb[r] + pc[r], 0.0f);
        oo[r] = o;
        yo[r] = fmaf(gamma, o, xv[r]);
    }
    *(f32x4*)&out[base] = yo;
    *(f32x4*)&out[(size_t)Mm + base] = oo;
    *(f32x4*)&out[(size_t)2 * Mm + base] = xv;
}

extern "C" void kernel_launch(void* const* d_in, const int* in_sizes, int n_in,
                              void* d_out, int out_size, void* d_ws, size_t ws_size,
                              hipStream_t stream) {
    const float* x       = (const float*)d_in[0];
    const float* gamma_p = (const float*)d_in[1];
    float* out = (float*)d_out;

    // ws layout (~12.6 MB): row_d (8x3200 f32, 128K reserved) | xt2 | xc2
    float* row_d = (float*)d_ws;
    u16* xt2 = (u16*)((char*)d_ws + (1 << 17));
    u16* xc2 = xt2 + (size_t)Bb * XT2B;

    hipMemsetAsync(row_d, 0, (size_t)Bb * Np * sizeof(float), stream);
    prep_kernel  <<<400, 256, 0, stream>>>(x, gamma_p, out, xt2, xc2, row_d);
    stats_kernel <<<3136, 256, 0, stream>>>(xt2, row_d);
    conv_kernel  <<<100, 256, 0, stream>>>(row_d);
    out_kernel   <<<1176, 256, 0, stream>>>(xt2, xc2, row_d, out);
    finish_kernel<<<3136, 256, 0, stream>>>(x, gamma_p, out);
}

// Round 6
// 195.630 us; speedup vs baseline: 1.0850x; 1.0850x over previous
//
#include <hip/hip_runtime.h>
#include <math.h>

#define Bb 8
#define Cc 128
#define Nn 3136                  // 56*56 real spatial
#define Np 3200                  // padded spatial (50 x 64)
#define NT 50                    // 64-row tiles per batch
#define Mm (Bb*Cc*Nn)            // elements per output tensor
#define PADV 72                  // s_pt row stride (u16): 144 B (9x16B)
#define L2E 1.44269504088896340736f
#define C44 (44.0f * L2E)        // shift 44 in log2 domain

// xt2: [b][T(50)][seg(16)][row(64)][8 u16]   seg = channel-chunk of 8
#define XT2B (NT*16*64*8)        // 409600 u16 per batch
// xc2: [b][T(50)][seg(8)][c(128)][8 u16]     seg = i-chunk of 8
#define XC2B (NT*8*128*8)        // 409600 u16 per batch

typedef unsigned short u16;
typedef unsigned int   u32;
typedef __attribute__((ext_vector_type(8)))  u16      u16x8;
typedef __attribute__((ext_vector_type(8)))  _Float16 f16x8;
typedef __attribute__((ext_vector_type(4)))  _Float16 f16x4;
typedef __attribute__((ext_vector_type(4)))  float    f32x4;
typedef __attribute__((ext_vector_type(16))) float    f32x16;

__device__ __forceinline__ float exp2fast(float x) {
#if __has_builtin(__builtin_amdgcn_exp2f)
    return __builtin_amdgcn_exp2f(x);
#else
    float r; asm("v_exp_f32 %0, %1" : "=v"(r) : "v"(x)); return r;
#endif
}

// ---------------------------------------------------------------------------
// Prep: x f32 -> fragment-major fp16 tiles xt2/xc2 (all later MFMA fragment
// loads are perfectly coalesced global loads). Slot3 = gamma; x-copy done in
// finish_kernel. grid 400 = 8 b * 50 n-blocks; nblk 49 zero-pads tile 49.
// ---------------------------------------------------------------------------
__global__ __launch_bounds__(256) void prep_kernel(const float* __restrict__ x,
                                                   const float* __restrict__ gamma_p,
                                                   float* __restrict__ out,
                                                   u16* __restrict__ xt2,
                                                   u16* __restrict__ xc2,
                                                   float* __restrict__ row_d) {
    const int bx = blockIdx.x;
    const int b = bx / 50, nblk = bx % 50;
    const int t = threadIdx.x;

    if (nblk == 49) {            // pad tile: rows 3136..3199 all zero
        const u16x8 z8 = {0, 0, 0, 0, 0, 0, 0, 0};
        u16* dt = xt2 + ((size_t)b * NT + 49) * (16 * 64 * 8);
        u16* dc = xc2 + ((size_t)b * NT + 49) * (8 * 128 * 8);
        #pragma unroll
        for (int it = 0; it < 4; ++it) {
            *(u16x8*)&dt[(it * 256 + t) * 8] = z8;
            *(u16x8*)&dc[(it * 256 + t) * 8] = z8;
        }
        if (t < 64) row_d[b * Np + Nn + t] = 1.0f;   // pad denominators: 1
        return;
    }

    __shared__ float lx[Cc][65];
    const int n0 = nblk * 64;

    // phase 1: coalesced read
    #pragma unroll 8
    for (int r = 0; r < 32; ++r) {
        const int c = r * 4 + (t >> 6);
        const int g = (b * Cc + c) * Nn + n0 + (t & 63);
        lx[c][t & 63] = x[g];
    }
    __syncthreads();

    // phase 2: xt2 — thread (row nl, cseg) -> segs cseg*4+k, fully coalesced
    {
        const int nl = t & 63, cseg = t >> 6;
        u16x8 hv[4];
        #pragma unroll
        for (int cc = 0; cc < 32; ++cc) {
            const _Float16 hh = (_Float16)lx[cseg * 32 + cc][nl];
            hv[cc >> 3][cc & 7] = __builtin_bit_cast(u16, hh);
        }
        u16* base = xt2 + (((size_t)(b * NT + nblk) * 16 + cseg * 4) * 64 + nl) * 8;
        #pragma unroll
        for (int k = 0; k < 4; ++k) *(u16x8*)&base[k * (64 * 8)] = hv[k];
    }
    // phase 2b: xc2 — thread (c, half) -> segs half*4+k
    {
        const int c = t >> 1, half = t & 1;
        u16x8 hv[4];
        #pragma unroll
        for (int k = 0; k < 32; ++k) {
            const _Float16 hh = (_Float16)lx[c][half * 32 + k];
            hv[k >> 3][k & 7] = __builtin_bit_cast(u16, hh);
        }
        u16* base = xc2 + (((size_t)(b * NT + nblk) * 8 + half * 4) * 128 + c) * 8;
        #pragma unroll
        for (int k = 0; k < 4; ++k) *(u16x8*)&base[k * (128 * 8)] = hv[k];
    }
    if (bx == 0 && t == 0) out[(size_t)3 * Mm] = gamma_p[0];
}

// ---------------------------------------------------------------------------
// Stats: row_d[b,i] += sum_j exp(e_ij - 44). (byte-identical to R5 verified)
// No LDS, no barriers, dual MFMA chains with correct seg pairing.
// grid 3136 = 49 i-blocks * 8 j-chunks * 8 b; (256,5).
// ---------------------------------------------------------------------------
__global__ __launch_bounds__(256, 5) void stats_kernel(const u16* __restrict__ xt2,
                                                       float* __restrict__ row_d) {
    const int bx = blockIdx.x;
    const int b = bx & 7, rem = bx >> 3;
    const int i0t = rem >> 3, jq = rem & 7;      // i-tile 0..48, j-chunk 0..7
    const int t = threadIdx.x;
    const int w = t >> 6, l = t & 63, lane = l & 31, h = l >> 5;
    const int igrp = w & 1, jsub = w >> 1;
    const u16* __restrict__ xb = xt2 + (size_t)b * XT2B;

    f16x8 Bf[8];                                 // resident i-row frags, seg 2kk+h
    const int irow = igrp * 32 + lane;
    #pragma unroll
    for (int kk = 0; kk < 8; ++kk)
        Bf[kk] = *(const f16x8*)&xb[(((size_t)i0t * 16 + 2 * kk + h) * 64 + irow) * 8];

    const int jt0 = jq * 6 + (jq < 2 ? jq : 2);  // 0,7,14,20,26,32,38,44
    const int jcnt = 6 + (jq < 2 ? 1 : 0);       // 7,7,6,6,6,6,6,6
    const int jrow = jsub * 32 + lane;

    float sa = 0.f, sb = 0.f;
    for (int jt = jt0; jt < jt0 + jcnt; ++jt) {
        const u16* ab = &xb[((size_t)jt * 16 * 64 + jrow) * 8];
        f32x16 ea, eb;
        #pragma unroll
        for (int r = 0; r < 16; ++r) { ea[r] = 0.f; eb[r] = 0.f; }
        __builtin_amdgcn_s_setprio(1);
        #pragma unroll
        for (int kk = 0; kk < 4; ++kk) {
            const f16x8 A0 = *(const f16x8*)&ab[(4 * kk + h) * 512];
            const f16x8 A1 = *(const f16x8*)&ab[(4 * kk + 2 + h) * 512];
            ea = __builtin_amdgcn_mfma_f32_32x32x16_f16(A0, Bf[2 * kk],     ea, 0, 0, 0);
            eb = __builtin_amdgcn_mfma_f32_32x32x16_f16(A1, Bf[2 * kk + 1], eb, 0, 0, 0);
        }
        __builtin_amdgcn_s_setprio(0);

        if (jt == i0t) {                          // diagonal tile: masked path
            const bool dsub = (jsub == igrp);
            #pragma unroll
            for (int r = 0; r < 16; ++r) {
                const int mrow = (r & 3) + 8 * (r >> 2) + 4 * h;
                float v = ea[r] + eb[r];
                if (dsub && mrow == lane) v = 0.f;
                const float e = exp2fast(fmaf(v, L2E, -C44));
                if (r & 1) sb += e; else sa += e;
            }
        } else {
            #pragma unroll
            for (int r = 0; r < 16; ++r) {
                const float e = exp2fast(fmaf(ea[r] + eb[r], L2E, -C44));
                if (r & 1) sb += e; else sa += e;
            }
        }
    }
    float ssum = sa + sb;
    ssum += __shfl_xor(ssum, 32, 64);   // combine h-halves (disjoint j-rows)
    if (h == 0) atomicAdd(&row_d[b * Np + i0t * 64 + igrp * 32 + lane], ssum);
}

// ---------------------------------------------------------------------------
// Conv: row_d -> c_i = 44*log2e + log2(d_i), so P = exp2(e*log2e - c_i).
// ---------------------------------------------------------------------------
__global__ __launch_bounds__(256) void conv_kernel(float* __restrict__ row_d) {
    const int i = blockIdx.x * 256 + threadIdx.x;
    row_d[i] = C44 + __log2f(row_d[i]);
}

// ---------------------------------------------------------------------------
// Out v6: R2 skeleton (grid 784 = 8 b * 49 j * 2 ih, P^T dbuf, 1 barrier/
// iter) + CROSS-ITERATION A register double-buffer: An (tile ti+1) issued at
// the top of iter ti, consumed only after loop-back -> a full iteration of
// covered L2 latency (hipcc cannot hoist loads across __syncthreads, so this
// must be done at source level). V loads moved to just-before-barrier
// (barrier wait + vmcnt drain covers them; short liveness keeps peak regs
// ~144 so 3 waves/SIMD survive). Energy = single acc chain (pays for An).
// Partials -> slots 0/1; finish combines.
// ---------------------------------------------------------------------------
__global__ __launch_bounds__(256, 3) void out_kernel(const u16* __restrict__ xt2,
                                                     const u16* __restrict__ xc2,
                                                     const float* __restrict__ row_c,
                                                     float* __restrict__ out) {
    __shared__ u16 s_pt[2][64 * PADV];           // P^T dbuf, 2 x 9216 B

    const int bx = blockIdx.x;
    const int b = bx & 7, rem = bx >> 3;         // rem 0..97
    const int j0t = rem >> 1, ih = rem & 1;      // j-tile 0..48, i-half
    const int ti0 = ih * 25, ti1 = ti0 + 25;
    const int t = threadIdx.x;
    const int w = t >> 6, l = t & 63, lane = l & 31, h = l >> 5;
    const int isub = w & 1, jgrp = w >> 1;       // energy roles
    const int jg = w & 1,  cp = w >> 1;          // PV roles
    const u16* __restrict__ xtb = xt2 + (size_t)b * XT2B;
    const u16* __restrict__ xcb = xc2 + (size_t)b * XC2B;

    f16x8 Bj[8];                                 // resident j-row frags, seg 2kk+h
    const int jrow = jgrp * 32 + lane;
    #pragma unroll
    for (int kk = 0; kk < 8; ++kk)
        Bj[kk] = *(const f16x8*)&xtb[(((size_t)j0t * 16 + 2 * kk + h) * 64 + jrow) * 8];

    f32x16 oa, ob;
    #pragma unroll
    for (int r = 0; r < 16; ++r) { oa[r] = 0.f; ob[r] = 0.f; }

    const int arow = isub * 32 + lane;
    const int ptbase = (jgrp * 32 + lane) * PADV + isub * 32;
    const int pbrow = (jg * 32 + lane) * PADV + h * 8;

    // prologue: A(ti0) into current buffer
    f16x8 Ac[8];
    {
        const u16* ab = &xtb[((size_t)ti0 * 16 * 64 + arow) * 8];
        #pragma unroll
        for (int kk = 0; kk < 8; ++kk)
            Ac[kk] = *(const f16x8*)&ab[(2 * kk + h) * 512];
    }

    for (int ti = ti0; ti < ti1; ++ti) {
        // issue NEXT-tile A loads first: consumed only after loop-back,
        // so they have the whole iteration to complete.
        const int tn = (ti + 1 < ti1) ? ti + 1 : ti;
        f16x8 An[8];
        const u16* abn = &xtb[((size_t)tn * 16 * 64 + arow) * 8];
        #pragma unroll
        for (int kk = 0; kk < 8; ++kk)
            An[kk] = *(const f16x8*)&abn[(2 * kk + h) * 512];

        // energy: D[m=i32][n=j32], K=128, operands all in registers
        f32x16 ea;
        #pragma unroll
        for (int r = 0; r < 16; ++r) ea[r] = 0.f;
        #pragma unroll
        for (int kk = 0; kk < 8; ++kk)
            ea = __builtin_amdgcn_mfma_f32_32x32x16_f16(Ac[kk], Bj[kk], ea, 0, 0, 0);

        // P = exp2(e*l2e - c_i) -> s_pt[ti&1]; diag branch hoisted
        u16* pt = &s_pt[ti & 1][0];
        const float* cbase = &row_c[b * Np + ti * 64 + isub * 32];
        if (ti == j0t) {
            const bool dsub = (isub == jgrp);
            #pragma unroll
            for (int qq = 0; qq < 4; ++qq) {
                const f32x4 cv = *(const f32x4*)&cbase[qq * 8 + h * 4];
                f16x4 pv;
                #pragma unroll
                for (int r = 0; r < 4; ++r) {
                    const int m = qq * 8 + h * 4 + r;
                    float v = ea[qq * 4 + r];
                    if (dsub && m == lane) v = 0.f;
                    pv[r] = (_Float16)exp2fast(fmaf(v, L2E, -cv[r]));
                }
                *(f16x4*)&pt[ptbase + qq * 8 + h * 4] = pv;
            }
        } else {
            #pragma unroll
            for (int qq = 0; qq < 4; ++qq) {
                const f32x4 cv = *(const f32x4*)&cbase[qq * 8 + h * 4];
                f16x4 pv;
                #pragma unroll
                for (int r = 0; r < 4; ++r)
                    pv[r] = (_Float16)exp2fast(fmaf(ea[qq * 4 + r], L2E, -cv[r]));
                *(f16x4*)&pt[ptbase + qq * 8 + h * 4] = pv;
            }
        }

        // V loads issued BEFORE the barrier: barrier wait + vmcnt drain
        // covers their latency; consumed right after.
        f16x8 Av[4][2];
        const u16* vb = &xcb[((size_t)ti * 8 * 128 + cp * 64 + lane) * 8];
        #pragma unroll
        for (int kk = 0; kk < 4; ++kk) {
            Av[kk][0] = *(const f16x8*)&vb[((2 * kk + h) * 128) * 8];
            Av[kk][1] = *(const f16x8*)&vb[((2 * kk + h) * 128 + 32) * 8];
        }
        __syncthreads();                         // s_pt[ti&1] complete

        // PV: D[m=c][n=j]; Bp from s_pt, V already in registers
        #pragma unroll
        for (int kk = 0; kk < 4; ++kk) {
            const f16x8 Bp = *(const f16x8*)&pt[pbrow + kk * 16];
            oa = __builtin_amdgcn_mfma_f32_32x32x16_f16(Av[kk][0], Bp, oa, 0, 0, 0);
            ob = __builtin_amdgcn_mfma_f32_32x32x16_f16(Av[kk][1], Bp, ob, 0, 0, 0);
        }

        // rotate A double-buffer
        #pragma unroll
        for (int kk = 0; kk < 8; ++kk) Ac[kk] = An[kk];
    }

    // epilogue: raw f32 partials -> out slot ih (scratch until finish_kernel)
    #pragma unroll
    for (int r = 0; r < 16; ++r) {
        const int mrow = (r & 3) + 8 * (r >> 2) + 4 * h;
        const int jj = j0t * 64 + jg * 32 + lane;
        {
            const int c = cp * 64 + mrow;
            const size_t pos = (size_t)(b * Cc + c) * Nn + jj;
            out[(size_t)ih * Mm + pos] = oa[r];
        }
        {
            const int c = cp * 64 + 32 + mrow;
            const size_t pos = (size_t)(b * Cc + c) * Nn + jj;
            out[(size_t)ih * Mm + pos] = ob[r];
        }
    }
}

// ---------------------------------------------------------------------------
// Finish: o = relu(p0 + p1); slot0 = gamma*o + x; slot1 = o; slot2 = x.
// Pure streaming: 38.6 MB read + 38.6 MB write.
// ---------------------------------------------------------------------------
__global__ __launch_bounds__(256) void finish_kernel(const float* __restrict__ x,
                                                     const float* __restrict__ gamma_p,
                                                     float* __restrict__ out) {
    const float gamma = gamma_p[0];
    const size_t base = ((size_t)blockIdx.x * 256 + threadIdx.x) * 4;
    const f32x4 pa = *(const f32x4*)&out[base];
    const f32x4 pb = *(const f32x4*)&out[(size_t)Mm + base];
    const f32x4 xv = *(const f32x4*)&x[base];
    f32x4 yo, oo;
    #pragma unroll
    for (int r = 0; r < 4; ++r) {
        const float o = fmaxf(pa[r] + pb[r], 0.0f);
        oo[r] = o;
        yo[r] = fmaf(gamma, o, xv[r]);
    }
    *(f32x4*)&out[base] = yo;
    *(f32x4*)&out[(size_t)Mm + base] = oo;
    *(f32x4*)&out[(size_t)2 * Mm + base] = xv;
}

extern "C" void kernel_launch(void* const* d_in, const int* in_sizes, int n_in,
                              void* d_out, int out_size, void* d_ws, size_t ws_size,
                              hipStream_t stream) {
    const float* x       = (const float*)d_in[0];
    const float* gamma_p = (const float*)d_in[1];
    float* out = (float*)d_out;

    // ws layout (~12.6 MB): row_d (8x3200 f32, 128K reserved) | xt2 | xc2
    float* row_d = (float*)d_ws;
    u16* xt2 = (u16*)((char*)d_ws + (1 << 17));
    u16* xc2 = xt2 + (size_t)Bb * XT2B;

    hipMemsetAsync(row_d, 0, (size_t)Bb * Np * sizeof(float), stream);
    prep_kernel  <<<400, 256, 0, stream>>>(x, gamma_p, out, xt2, xc2, row_d);
    stats_kernel <<<3136, 256, 0, stream>>>(xt2, row_d);
    conv_kernel  <<<100, 256, 0, stream>>>(row_d);
    out_kernel   <<<784, 256, 0, stream>>>(xt2, xc2, row_d, out);
    finish_kernel<<<3136, 256, 0, stream>>>(x, gamma_p, out);
}

// Round 7
// 191.608 us; speedup vs baseline: 1.1078x; 1.0210x over previous
//
#include <hip/hip_runtime.h>
#include <math.h>

#define Bb 8
#define Cc 128
#define Nn 3136                  // 56*56 real spatial
#define Np 3200                  // padded spatial (50 x 64)
#define NT 50                    // 64-row tiles per batch
#define Mm (Bb*Cc*Nn)            // elements per output tensor
#define PADV 72                  // s_pt row stride (u16): 144 B (9x16B)
#define L2E 1.44269504088896340736f
#define C44 (44.0f * L2E)        // shift 44 in log2 domain

// xt2: [b][T(50)][seg(16)][row(64)][8 u16]   seg = channel-chunk of 8
#define XT2B (NT*16*64*8)        // 409600 u16 per batch
#define TSZA (16*64*8)           // 8192 u16 = 16 KB per A tile
// xc2: [b][T(50)][seg(8)][c(128)][8 u16]     seg = i-chunk of 8
#define XC2B (NT*8*128*8)        // 409600 u16 per batch
#define TSZV (8*128*8)           // 8192 u16 = 16 KB per V tile

typedef unsigned short u16;
typedef unsigned int   u32;
typedef __attribute__((ext_vector_type(8)))  u16      u16x8;
typedef __attribute__((ext_vector_type(8)))  _Float16 f16x8;
typedef __attribute__((ext_vector_type(4)))  _Float16 f16x4;
typedef __attribute__((ext_vector_type(4)))  float    f32x4;
typedef __attribute__((ext_vector_type(16))) float    f32x16;

__device__ __forceinline__ float exp2fast(float x) {
#if __has_builtin(__builtin_amdgcn_exp2f)
    return __builtin_amdgcn_exp2f(x);
#else
    float r; asm("v_exp_f32 %0, %1" : "=v"(r) : "v"(x)); return r;
#endif
}

// global -> LDS direct copy, 16 B per lane; LDS dest must be wave-uniform
// (hardware adds lane*16), global src is per-lane.
typedef __attribute__((address_space(1))) const unsigned int gas_u32;
typedef __attribute__((address_space(3))) unsigned int las_u32;
__device__ __forceinline__ void gload_lds16(const u16* g, u16* l) {
    __builtin_amdgcn_global_load_lds((gas_u32*)g, (las_u32*)l, 16, 0, 0);
}

// ---------------------------------------------------------------------------
// Prep: x f32 -> fragment-major fp16 tiles xt2/xc2 (all later MFMA fragment
// loads / LDS stages are perfectly coalesced). Slot3 = gamma; x-copy done in
// finish_kernel. grid 400 = 8 b * 50 n-blocks; nblk 49 zero-pads tile 49.
// ---------------------------------------------------------------------------
__global__ __launch_bounds__(256) void prep_kernel(const float* __restrict__ x,
                                                   const float* __restrict__ gamma_p,
                                                   float* __restrict__ out,
                                                   u16* __restrict__ xt2,
                                                   u16* __restrict__ xc2,
                                                   float* __restrict__ row_d) {
    const int bx = blockIdx.x;
    const int b = bx / 50, nblk = bx % 50;
    const int t = threadIdx.x;

    if (nblk == 49) {            // pad tile: rows 3136..3199 all zero
        const u16x8 z8 = {0, 0, 0, 0, 0, 0, 0, 0};
        u16* dt = xt2 + ((size_t)b * NT + 49) * TSZA;
        u16* dc = xc2 + ((size_t)b * NT + 49) * TSZV;
        #pragma unroll
        for (int it = 0; it < 4; ++it) {
            *(u16x8*)&dt[(it * 256 + t) * 8] = z8;
            *(u16x8*)&dc[(it * 256 + t) * 8] = z8;
        }
        if (t < 64) row_d[b * Np + Nn + t] = 1.0f;   // pad denominators: 1
        return;
    }

    __shared__ float lx[Cc][65];
    const int n0 = nblk * 64;

    // phase 1: coalesced read
    #pragma unroll 8
    for (int r = 0; r < 32; ++r) {
        const int c = r * 4 + (t >> 6);
        const int g = (b * Cc + c) * Nn + n0 + (t & 63);
        lx[c][t & 63] = x[g];
    }
    __syncthreads();

    // phase 2: xt2 — thread (row nl, cseg) -> segs cseg*4+k, fully coalesced
    {
        const int nl = t & 63, cseg = t >> 6;
        u16x8 hv[4];
        #pragma unroll
        for (int cc = 0; cc < 32; ++cc) {
            const _Float16 hh = (_Float16)lx[cseg * 32 + cc][nl];
            hv[cc >> 3][cc & 7] = __builtin_bit_cast(u16, hh);
        }
        u16* base = xt2 + (((size_t)(b * NT + nblk) * 16 + cseg * 4) * 64 + nl) * 8;
        #pragma unroll
        for (int k = 0; k < 4; ++k) *(u16x8*)&base[k * (64 * 8)] = hv[k];
    }
    // phase 2b: xc2 — thread (c, half) -> segs half*4+k
    {
        const int c = t >> 1, half = t & 1;
        u16x8 hv[4];
        #pragma unroll
        for (int k = 0; k < 32; ++k) {
            const _Float16 hh = (_Float16)lx[c][half * 32 + k];
            hv[k >> 3][k & 7] = __builtin_bit_cast(u16, hh);
        }
        u16* base = xc2 + (((size_t)(b * NT + nblk) * 8 + half * 4) * 128 + c) * 8;
        #pragma unroll
        for (int k = 0; k < 4; ++k) *(u16x8*)&base[k * (128 * 8)] = hv[k];
    }
    if (bx == 0 && t == 0) out[(size_t)3 * Mm] = gamma_p[0];
}

// ---------------------------------------------------------------------------
// Stats: row_d[b,i] += sum_j exp(e_ij - 44). j-tile staged ONCE per iter via
// global_load_lds (16 KB, vs 32 KB duplicated VGPR loads before) into a
// double buffer; 1 barrier/iter (stage(nxt) -> compute(cur) -> barrier).
// Dual MFMA chains, verified seg pairing (chain-a seg 4kk+h w/ Bf[2kk],
// chain-b seg 4kk+2+h w/ Bf[2kk+1]). grid 3136 = 49 i * 8 jq * 8 b.
// ---------------------------------------------------------------------------
__global__ __launch_bounds__(256, 4) void stats_kernel(const u16* __restrict__ xt2,
                                                       float* __restrict__ row_d) {
    __shared__ __align__(16) u16 s_j[2][TSZA];   // 2 x 16 KB

    const int bx = blockIdx.x;
    const int b = bx & 7, rem = bx >> 3;
    const int i0t = rem >> 3, jq = rem & 7;      // i-tile 0..48, j-chunk 0..7
    const int t = threadIdx.x;
    const int w = t >> 6, l = t & 63, lane = l & 31, h = l >> 5;
    const int igrp = w & 1, jsub = w >> 1;
    const u16* __restrict__ xb = xt2 + (size_t)b * XT2B;

    f16x8 Bf[8];                                 // resident i-row frags, seg 2kk+h
    const int irow = igrp * 32 + lane;
    #pragma unroll
    for (int kk = 0; kk < 8; ++kk)
        Bf[kk] = *(const f16x8*)&xb[(((size_t)i0t * 16 + 2 * kk + h) * 64 + irow) * 8];

    const int jt0 = jq * 6 + (jq < 2 ? jq : 2);  // 0,7,14,20,26,32,38,44
    const int jcnt = 6 + (jq < 2 ? 1 : 0);       // 7,7,6,6,6,6,6,6
    const int jrow = jsub * 32 + lane;
    const int wsh = w * 2048;                    // this wave's 4 KB of the tile

    // prologue stage: tile jt0 -> buf 0
    {
        const u16* gs = xb + (size_t)jt0 * TSZA + wsh + l * 8;
        u16* ls = &s_j[0][wsh];
        #pragma unroll
        for (int k = 0; k < 4; ++k) gload_lds16(gs + k * 512, ls + k * 512);
    }
    __syncthreads();

    float sa = 0.f, sb = 0.f;
    for (int jt = jt0; jt < jt0 + jcnt; ++jt) {
        const int cur = (jt - jt0) & 1;
        if (jt + 1 < jt0 + jcnt) {               // stage next tile -> other buf
            const u16* gs = xb + (size_t)(jt + 1) * TSZA + wsh + l * 8;
            u16* ls = &s_j[cur ^ 1][wsh];
            #pragma unroll
            for (int k = 0; k < 4; ++k) gload_lds16(gs + k * 512, ls + k * 512);
        }

        const u16* sj = &s_j[cur][0];
        f32x16 ea, eb;
        #pragma unroll
        for (int r = 0; r < 16; ++r) { ea[r] = 0.f; eb[r] = 0.f; }
        __builtin_amdgcn_s_setprio(1);
        #pragma unroll
        for (int kk = 0; kk < 4; ++kk) {
            const f16x8 A0 = *(const f16x8*)&sj[((4 * kk + h) * 64 + jrow) * 8];
            const f16x8 A1 = *(const f16x8*)&sj[((4 * kk + 2 + h) * 64 + jrow) * 8];
            ea = __builtin_amdgcn_mfma_f32_32x32x16_f16(A0, Bf[2 * kk],     ea, 0, 0, 0);
            eb = __builtin_amdgcn_mfma_f32_32x32x16_f16(A1, Bf[2 * kk + 1], eb, 0, 0, 0);
        }
        __builtin_amdgcn_s_setprio(0);

        if (jt == i0t) {                          // diagonal tile: masked path
            const bool dsub = (jsub == igrp);
            #pragma unroll
            for (int r = 0; r < 16; ++r) {
                const int mrow = (r & 3) + 8 * (r >> 2) + 4 * h;
                float v = ea[r] + eb[r];
                if (dsub && mrow == lane) v = 0.f;
                const float e = exp2fast(fmaf(v, L2E, -C44));
                if (r & 1) sb += e; else sa += e;
            }
        } else {
            #pragma unroll
            for (int r = 0; r < 16; ++r) {
                const float e = exp2fast(fmaf(ea[r] + eb[r], L2E, -C44));
                if (r & 1) sb += e; else sa += e;
            }
        }
        __syncthreads();       // nxt staged (vmcnt drain) + cur free to overwrite
    }
    float ssum = sa + sb;
    ssum += __shfl_xor(ssum, 32, 64);   // combine h-halves (disjoint j-rows)
    if (h == 0) atomicAdd(&row_d[b * Np + i0t * 64 + igrp * 32 + lane], ssum);
}

// ---------------------------------------------------------------------------
// Conv: row_d -> c_i = 44*log2e + log2(d_i), so P = exp2(e*log2e - c_i).
// ---------------------------------------------------------------------------
__global__ __launch_bounds__(256) void conv_kernel(float* __restrict__ row_d) {
    const int i = blockIdx.x * 256 + threadIdx.x;
    row_d[i] = C44 + __log2f(row_d[i]);
}

// ---------------------------------------------------------------------------
// Out v7: LDS-broadcast operands. A+V tiles staged once per iter via
// global_load_lds (32 KB/block-iter vs 64 KB duplicated VGPR loads: the
// ROUND-6 diagnosis was VMEM-return-bandwidth bound, ~23 B/cy/CU achieved).
// Double-buffered A/V (stage(ti+1) issued at iter top, lands by B1's drain,
// covered by energy+exp); single P^T buffer (B2 protects it). 2 barriers/
// iter. grid 784 = 8 b * 49 j * 2 ih; LDS 73 KB -> 2 blocks/CU.
// Partials -> slots 0/1; finish combines.
// ---------------------------------------------------------------------------
__global__ __launch_bounds__(256, 2) void out_kernel(const u16* __restrict__ xt2,
                                                     const u16* __restrict__ xc2,
                                                     const float* __restrict__ row_c,
                                                     float* __restrict__ out) {
    __shared__ __align__(16) u16 s_xa[2][TSZA];  // 2 x 16 KB  A tiles (linear)
    __shared__ __align__(16) u16 s_xv[2][TSZV];  // 2 x 16 KB  V tiles (linear)
    __shared__ __align__(16) u16 s_pt[64 * PADV];// 9216 B     P^T

    const int bx = blockIdx.x;
    const int b = bx & 7, rem = bx >> 3;         // rem 0..97
    const int j0t = rem >> 1, ih = rem & 1;      // j-tile 0..48, i-half
    const int ti0 = ih * 25, ti1 = ti0 + 25;
    const int t = threadIdx.x;
    const int w = t >> 6, l = t & 63, lane = l & 31, h = l >> 5;
    const int isub = w & 1, jgrp = w >> 1;       // energy roles
    const int jg = w & 1,  cp = w >> 1;          // PV roles
    const u16* __restrict__ xtb = xt2 + (size_t)b * XT2B;
    const u16* __restrict__ xcb = xc2 + (size_t)b * XC2B;

    f16x8 Bj[8];                                 // resident j-row frags, seg 2kk+h
    const int jrow = jgrp * 32 + lane;
    #pragma unroll
    for (int kk = 0; kk < 8; ++kk)
        Bj[kk] = *(const f16x8*)&xtb[(((size_t)j0t * 16 + 2 * kk + h) * 64 + jrow) * 8];

    f32x16 oa, ob;
    #pragma unroll
    for (int r = 0; r < 16; ++r) { oa[r] = 0.f; ob[r] = 0.f; }

    const int arow = isub * 32 + lane;
    const int ptbase = (jgrp * 32 + lane) * PADV + isub * 32;
    const int pbrow = (jg * 32 + lane) * PADV + h * 8;

    // staging roles: waves 0,1 -> A halves; waves 2,3 -> V halves (8 KB each)
    const bool wA = (w < 2);
    const int sh = (w & 1) * 4096;               // u16 offset of wave's 8 KB half

    // prologue stage: tile ti0 -> buf 0
    {
        const u16* gs = (wA ? xtb + (size_t)ti0 * TSZA : xcb + (size_t)ti0 * TSZV)
                        + sh + l * 8;
        u16* ls = (wA ? &s_xa[0][0] : &s_xv[0][0]) + sh;
        #pragma unroll
        for (int k = 0; k < 8; ++k) gload_lds16(gs + k * 512, ls + k * 512);
    }
    __syncthreads();

    for (int ti = ti0; ti < ti1; ++ti) {
        const int cur = (ti - ti0) & 1;
        if (ti + 1 < ti1) {                      // stage next tile -> other buf
            const u16* gs = (wA ? xtb + (size_t)(ti + 1) * TSZA
                                : xcb + (size_t)(ti + 1) * TSZV) + sh + l * 8;
            u16* ls = (wA ? &s_xa[cur ^ 1][0] : &s_xv[cur ^ 1][0]) + sh;
            #pragma unroll
            for (int k = 0; k < 8; ++k) gload_lds16(gs + k * 512, ls + k * 512);
        }

        // energy: D[m=i32][n=j32], K=128; A-frags from LDS (broadcast)
        const u16* sa = &s_xa[cur][0];
        f32x16 ea;
        #pragma unroll
        for (int r = 0; r < 16; ++r) ea[r] = 0.f;
        __builtin_amdgcn_s_setprio(1);
        #pragma unroll
        for (int kk = 0; kk < 8; ++kk) {
            const f16x8 A = *(const f16x8*)&sa[((2 * kk + h) * 64 + arow) * 8];
            ea = __builtin_amdgcn_mfma_f32_32x32x16_f16(A, Bj[kk], ea, 0, 0, 0);
        }
        __builtin_amdgcn_s_setprio(0);

        // P = exp2(e*l2e - c_i) -> s_pt; diag branch hoisted
        const float* cbase = &row_c[b * Np + ti * 64 + isub * 32];
        if (ti == j0t) {
            const bool dsub = (isub == jgrp);
            #pragma unroll
            for (int qq = 0; qq < 4; ++qq) {
                const f32x4 cv = *(const f32x4*)&cbase[qq * 8 + h * 4];
                f16x4 pv;
                #pragma unroll
                for (int r = 0; r < 4; ++r) {
                    const int m = qq * 8 + h * 4 + r;
                    float v = ea[qq * 4 + r];
                    if (dsub && m == lane) v = 0.f;
                    pv[r] = (_Float16)exp2fast(fmaf(v, L2E, -cv[r]));
                }
                *(f16x4*)&s_pt[ptbase + qq * 8 + h * 4] = pv;
            }
        } else {
            #pragma unroll
            for (int qq = 0; qq < 4; ++qq) {
                const f32x4 cv = *(const f32x4*)&cbase[qq * 8 + h * 4];
                f16x4 pv;
                #pragma unroll
                for (int r = 0; r < 4; ++r)
                    pv[r] = (_Float16)exp2fast(fmaf(ea[qq * 4 + r], L2E, -cv[r]));
                *(f16x4*)&s_pt[ptbase + qq * 8 + h * 4] = pv;
            }
        }
        __syncthreads();     // B1: P^T ready (also drains stage vmcnt)

        // PV: D[m=c][n=j]; V-frags + Bp from LDS
        const u16* sv = &s_xv[cur][0];
        __builtin_amdgcn_s_setprio(1);
        #pragma unroll
        for (int kk = 0; kk < 4; ++kk) {
            const f16x8 Bp  = *(const f16x8*)&s_pt[pbrow + kk * 16];
            const f16x8 Av0 = *(const f16x8*)&sv[((2 * kk + h) * 128 + cp * 64 + lane) * 8];
            const f16x8 Av1 = *(const f16x8*)&sv[((2 * kk + h) * 128 + cp * 64 + 32 + lane) * 8];
            oa = __builtin_amdgcn_mfma_f32_32x32x16_f16(Av0, Bp, oa, 0, 0, 0);
            ob = __builtin_amdgcn_mfma_f32_32x32x16_f16(Av1, Bp, ob, 0, 0, 0);
        }
        __builtin_amdgcn_s_setprio(0);
        __syncthreads();     // B2: cur A/V free for overwrite, P free
    }

    // epilogue: raw f32 partials -> out slot ih (scratch until finish_kernel)
    #pragma unroll
    for (int r = 0; r < 16; ++r) {
        const int mrow = (r & 3) + 8 * (r >> 2) + 4 * h;
        const int jj = j0t * 64 + jg * 32 + lane;
        {
            const int c = cp * 64 + mrow;
            const size_t pos = (size_t)(b * Cc + c) * Nn + jj;
            out[(size_t)ih * Mm + pos] = oa[r];
        }
        {
            const int c = cp * 64 + 32 + mrow;
            const size_t pos = (size_t)(b * Cc + c) * Nn + jj;
            out[(size_t)ih * Mm + pos] = ob[r];
        }
    }
}

// ---------------------------------------------------------------------------
// Finish: o = relu(p0 + p1); slot0 = gamma*o + x; slot1 = o; slot2 = x.
// Pure streaming: 38.6 MB read + 38.6 MB write.
// ---------------------------------------------------------------------------
__global__ __launch_bounds__(256) void finish_kernel(const float* __restrict__ x,
                                                     const float* __restrict__ gamma_p,
                                                     float* __restrict__ out) {
    const float gamma = gamma_p[0];
    const size_t base = ((size_t)blockIdx.x * 256 + threadIdx.x) * 4;
    const f32x4 pa = *(const f32x4*)&out[base];
    const f32x4 pb = *(const f32x4*)&out[(size_t)Mm + base];
    const f32x4 xv = *(const f32x4*)&x[base];
    f32x4 yo, oo;
    #pragma unroll
    for (int r = 0; r < 4; ++r) {
        const float o = fmaxf(pa[r] + pb[r], 0.0f);
        oo[r] = o;
        yo[r] = fmaf(gamma, o, xv[r]);
    }
    *(f32x4*)&out[base] = yo;
    *(f32x4*)&out[(size_t)Mm + base] = oo;
    *(f32x4*)&out[(size_t)2 * Mm + base] = xv;
}

extern "C" void kernel_launch(void* const* d_in, const int* in_sizes, int n_in,
                              void* d_out, int out_size, void* d_ws, size_t ws_size,
                              hipStream_t stream) {
    const float* x       = (const float*)d_in[0];
    const float* gamma_p = (const float*)d_in[1];
    float* out = (float*)d_out;

    // ws layout (~12.6 MB): row_d (8x3200 f32, 128K reserved) | xt2 | xc2
    float* row_d = (float*)d_ws;
    u16* xt2 = (u16*)((char*)d_ws + (1 << 17));
    u16* xc2 = xt2 + (size_t)Bb * XT2B;

    hipMemsetAsync(row_d, 0, (size_t)Bb * Np * sizeof(float), stream);
    prep_kernel  <<<400, 256, 0, stream>>>(x, gamma_p, out, xt2, xc2, row_d);
    stats_kernel <<<3136, 256, 0, stream>>>(xt2, row_d);
    conv_kernel  <<<100, 256, 0, stream>>>(row_d);
    out_kernel   <<<784, 256, 0, stream>>>(xt2, xc2, row_d, out);
    finish_kernel<<<3136, 256, 0, stream>>>(x, gamma_p, out);
}

// Round 8
// 191.356 us; speedup vs baseline: 1.1093x; 1.0013x over previous
//
#include <hip/hip_runtime.h>
#include <math.h>

#define Bb 8
#define Cc 128
#define Nn 3136                  // 56*56 real spatial
#define Np 3200                  // padded spatial (50 x 64)
#define NT 50                    // 64-row tiles per batch
#define Mm (Bb*Cc*Nn)            // elements per output tensor
#define PADV 72                  // s_pt row stride (u16): 144 B (9x16B)
#define L2E 1.44269504088896340736f
#define C44 (44.0f * L2E)        // shift 44 in log2 domain

// xt2: [b][T(50)][seg(16)][row(64)][8 u16]   seg = channel-chunk of 8
#define XT2B (NT*16*64*8)        // 409600 u16 per batch
#define TSZA (16*64*8)           // 8192 u16 = 16 KB per A tile
// xc2: [b][T(50)][seg(8)][c(128)][8 u16]     seg = i-chunk of 8
#define XC2B (NT*8*128*8)        // 409600 u16 per batch
#define TSZV (8*128*8)           // 8192 u16 = 16 KB per V tile

typedef unsigned short u16;
typedef unsigned int   u32;
typedef __attribute__((ext_vector_type(8)))  u16      u16x8;
typedef __attribute__((ext_vector_type(8)))  _Float16 f16x8;
typedef __attribute__((ext_vector_type(4)))  _Float16 f16x4;
typedef __attribute__((ext_vector_type(4)))  float    f32x4;
typedef __attribute__((ext_vector_type(16))) float    f32x16;

__device__ __forceinline__ float exp2fast(float x) {
#if __has_builtin(__builtin_amdgcn_exp2f)
    return __builtin_amdgcn_exp2f(x);
#else
    float r; asm("v_exp_f32 %0, %1" : "=v"(r) : "v"(x)); return r;
#endif
}

// global -> LDS direct copy, 16 B per lane; LDS dest wave-uniform.
typedef __attribute__((address_space(1))) const unsigned int gas_u32;
typedef __attribute__((address_space(3))) unsigned int las_u32;
__device__ __forceinline__ void gload_lds16(const u16* g, u16* l) {
    __builtin_amdgcn_global_load_lds((gas_u32*)g, (las_u32*)l, 16, 0, 0);
}

#define BAR()    __builtin_amdgcn_s_barrier()
#define SCHED0() __builtin_amdgcn_sched_barrier(0)
#define W_LGKM() asm volatile("s_waitcnt lgkmcnt(0)" ::: "memory")
#define W_ALL()  asm volatile("s_waitcnt vmcnt(0) lgkmcnt(0)" ::: "memory")
#define W_VM4()  asm volatile("s_waitcnt vmcnt(4) lgkmcnt(0)" ::: "memory")

// ---------------------------------------------------------------------------
// Prep: x f32 -> fragment-major fp16 tiles xt2/xc2. Slot3 = gamma; x-copy in
// finish. grid 400 = 8 b * 50 n-blocks; nblk 49 zero-pads tile 49.
// ---------------------------------------------------------------------------
__global__ __launch_bounds__(256) void prep_kernel(const float* __restrict__ x,
                                                   const float* __restrict__ gamma_p,
                                                   float* __restrict__ out,
                                                   u16* __restrict__ xt2,
                                                   u16* __restrict__ xc2,
                                                   float* __restrict__ row_d) {
    const int bx = blockIdx.x;
    const int b = bx / 50, nblk = bx % 50;
    const int t = threadIdx.x;

    if (nblk == 49) {            // pad tile: rows 3136..3199 all zero
        const u16x8 z8 = {0, 0, 0, 0, 0, 0, 0, 0};
        u16* dt = xt2 + ((size_t)b * NT + 49) * TSZA;
        u16* dc = xc2 + ((size_t)b * NT + 49) * TSZV;
        #pragma unroll
        for (int it = 0; it < 4; ++it) {
            *(u16x8*)&dt[(it * 256 + t) * 8] = z8;
            *(u16x8*)&dc[(it * 256 + t) * 8] = z8;
        }
        if (t < 64) row_d[b * Np + Nn + t] = 1.0f;   // pad denominators: 1
        return;
    }

    __shared__ float lx[Cc][65];
    const int n0 = nblk * 64;

    #pragma unroll 8
    for (int r = 0; r < 32; ++r) {
        const int c = r * 4 + (t >> 6);
        const int g = (b * Cc + c) * Nn + n0 + (t & 63);
        lx[c][t & 63] = x[g];
    }
    __syncthreads();

    {   // xt2: thread (row nl, cseg) -> segs cseg*4+k
        const int nl = t & 63, cseg = t >> 6;
        u16x8 hv[4];
        #pragma unroll
        for (int cc = 0; cc < 32; ++cc) {
            const _Float16 hh = (_Float16)lx[cseg * 32 + cc][nl];
            hv[cc >> 3][cc & 7] = __builtin_bit_cast(u16, hh);
        }
        u16* base = xt2 + (((size_t)(b * NT + nblk) * 16 + cseg * 4) * 64 + nl) * 8;
        #pragma unroll
        for (int k = 0; k < 4; ++k) *(u16x8*)&base[k * (64 * 8)] = hv[k];
    }
    {   // xc2: thread (c, half) -> segs half*4+k
        const int c = t >> 1, half = t & 1;
        u16x8 hv[4];
        #pragma unroll
        for (int k = 0; k < 32; ++k) {
            const _Float16 hh = (_Float16)lx[c][half * 32 + k];
            hv[k >> 3][k & 7] = __builtin_bit_cast(u16, hh);
        }
        u16* base = xc2 + (((size_t)(b * NT + nblk) * 8 + half * 4) * 128 + c) * 8;
        #pragma unroll
        for (int k = 0; k < 4; ++k) *(u16x8*)&base[k * (128 * 8)] = hv[k];
    }
    if (bx == 0 && t == 0) out[(size_t)3 * Mm] = gamma_p[0];
}

// ---------------------------------------------------------------------------
// Stats v8: TWO resident i-tiles {ip, ip+25} per block (staged j-tile feeds
// 2x the MFMAs -> stage bytes per FLOP halved; attacks the ~8 TB/s L3
// ceiling). 3-deep LDS pipeline, counted vmcnt(4) (T4: never drain to 0
// mid-loop). Seq per-tile dual chains (verified seg pairing). 1 barrier/iter.
// grid 1600 = 8 b * 25 ip * 8 jq. Pad i-tile 49 sums are harmless (V=0).
// ---------------------------------------------------------------------------
__global__ __launch_bounds__(256, 3) void stats_kernel(const u16* __restrict__ xt2,
                                                       float* __restrict__ row_d) {
    __shared__ __align__(16) u16 s_j[3][TSZA];   // 3 x 16 KB

    const int bx = blockIdx.x;
    const int b = bx & 7, rem = bx >> 3;
    const int ip = rem >> 3, jq = rem & 7;       // i-pair 0..24, j-chunk 0..7
    const int itA = ip, itB = ip + 25;
    const int t = threadIdx.x;
    const int w = t >> 6, l = t & 63, lane = l & 31, h = l >> 5;
    const int igrp = w & 1, jsub = w >> 1;
    const u16* __restrict__ xb = xt2 + (size_t)b * XT2B;

    f16x8 Bf[2][8];                              // resident i-row frags, seg 2kk+h
    const int irow = igrp * 32 + lane;
    #pragma unroll
    for (int s = 0; s < 2; ++s) {
        const int it = s ? itB : itA;
        #pragma unroll
        for (int kk = 0; kk < 8; ++kk)
            Bf[s][kk] = *(const f16x8*)&xb[(((size_t)it * 16 + 2 * kk + h) * 64 + irow) * 8];
    }

    const int jt0 = jq * 6 + (jq < 2 ? jq : 2);  // 0,7,14,20,26,32,38,44
    const int jcnt = 6 + (jq < 2 ? 1 : 0);       // 7,7,6,6,6,6,6,6
    const int jrow = jsub * 32 + lane;
    const int wsh = w * 2048;                    // wave's 4 KB region

    // prologue: stage jt0 -> b0, jt0+1 -> b1
    {
        const u16* gs = xb + (size_t)jt0 * TSZA + wsh + l * 8;
        u16* ls = &s_j[0][wsh];
        #pragma unroll
        for (int k = 0; k < 4; ++k) gload_lds16(gs + k * 512, ls + k * 512);
    }
    if (jcnt > 1) {
        const u16* gs = xb + (size_t)(jt0 + 1) * TSZA + wsh + l * 8;
        u16* ls = &s_j[1][wsh];
        #pragma unroll
        for (int k = 0; k < 4; ++k) gload_lds16(gs + k * 512, ls + k * 512);
        W_VM4();
    } else {
        W_ALL();
    }
    BAR(); SCHED0();

    float sA = 0.f, sB = 0.f;
    for (int k = 0; k < jcnt; ++k) {
        const int jt = jt0 + k, cur = k % 3;
        const bool more = (k + 2 < jcnt);
        if (more) {                              // stage jt+2 -> buf (k+2)%3
            const u16* gs = xb + (size_t)(jt + 2) * TSZA + wsh + l * 8;
            u16* ls = &s_j[(k + 2) % 3][wsh];
            #pragma unroll
            for (int kq = 0; kq < 4; ++kq) gload_lds16(gs + kq * 512, ls + kq * 512);
        }

        const u16* sj = &s_j[cur][0];
        #pragma unroll
        for (int s = 0; s < 2; ++s) {
            f32x16 ea, eb;
            #pragma unroll
            for (int r = 0; r < 16; ++r) { ea[r] = 0.f; eb[r] = 0.f; }
            __builtin_amdgcn_s_setprio(1);
            #pragma unroll
            for (int kk = 0; kk < 4; ++kk) {
                const f16x8 A0 = *(const f16x8*)&sj[((4 * kk + h) * 64 + jrow) * 8];
                const f16x8 A1 = *(const f16x8*)&sj[((4 * kk + 2 + h) * 64 + jrow) * 8];
                ea = __builtin_amdgcn_mfma_f32_32x32x16_f16(A0, Bf[s][2 * kk],     ea, 0, 0, 0);
                eb = __builtin_amdgcn_mfma_f32_32x32x16_f16(A1, Bf[s][2 * kk + 1], eb, 0, 0, 0);
            }
            __builtin_amdgcn_s_setprio(0);

            float acc = 0.f;
            const bool diag = (jt == (s ? itB : itA)) && (jsub == igrp);
            #pragma unroll
            for (int r = 0; r < 16; ++r) {
                const int mrow = (r & 3) + 8 * (r >> 2) + 4 * h;
                float v = ea[r] + eb[r];
                if (diag && mrow == lane) v = 0.f;
                acc += exp2fast(fmaf(v, L2E, -C44));
            }
            if (s) sB += acc; else sA += acc;
        }

        if (more) { W_VM4(); } else { W_ALL(); }
        BAR(); SCHED0();
    }
    sA += __shfl_xor(sA, 32, 64);   // combine h-halves (disjoint j-rows)
    sB += __shfl_xor(sB, 32, 64);
    if (h == 0) {
        atomicAdd(&row_d[b * Np + itA * 64 + igrp * 32 + lane], sA);
        atomicAdd(&row_d[b * Np + itB * 64 + igrp * 32 + lane], sB);
    }
}

// ---------------------------------------------------------------------------
// Conv: row_d -> c_i = 44*log2e + log2(d_i), so P = exp2(e*log2e - c_i).
// ---------------------------------------------------------------------------
__global__ __launch_bounds__(256) void conv_kernel(float* __restrict__ row_d) {
    const int i = blockIdx.x * 256 + threadIdx.x;
    row_d[i] = C44 + __log2f(row_d[i]);
}

// ---------------------------------------------------------------------------
// Out v8: TWO resident j-tiles {2jp, 2jp+1} per block -> each staged A/V
// tile feeds 32 MFMA/wave (stage bytes per FLOP halved). Raw s_barrier +
// lgkmcnt-only waits between the 4 phases; SINGLE vmcnt(0) drain per iter
// at the end (stage in flight across all 4 phases = T4). 3-way i-split.
// grid 600 = 8 b * 25 jp * 3 q; LDS 74752 -> 2 blocks/CU. Partials ->
// slots 0/1/2; jtB==49 (pad) stores skipped.
// ---------------------------------------------------------------------------
__global__ __launch_bounds__(256, 2) void out_kernel(const u16* __restrict__ xt2,
                                                     const u16* __restrict__ xc2,
                                                     const float* __restrict__ row_c,
                                                     float* __restrict__ out) {
    __shared__ __align__(16) u16 s_xa[2][TSZA];  // 2 x 16 KB  A tiles
    __shared__ __align__(16) u16 s_xv[2][TSZV];  // 2 x 16 KB  V tiles
    __shared__ __align__(16) u16 s_pt[64 * PADV];// 9216 B     P^T (shared by phases)

    const int bx = blockIdx.x;
    const int b = bx & 7, rem = bx >> 3;         // rem 0..74
    const int jp = rem / 3, q = rem % 3;         // j-pair 0..24, i-third
    const int jtA = 2 * jp, jtB = 2 * jp + 1;
    const int ti0 = q * 17;
    const int ti1 = (q == 2) ? 50 : ti0 + 17;    // 17/17/16 tiles
    const int t = threadIdx.x;
    const int w = t >> 6, l = t & 63, lane = l & 31, h = l >> 5;
    const int isub = w & 1, jgrp = w >> 1;       // energy roles
    const int jg = w & 1,  cp = w >> 1;          // PV roles
    const u16* __restrict__ xtb = xt2 + (size_t)b * XT2B;
    const u16* __restrict__ xcb = xc2 + (size_t)b * XC2B;

    f16x8 Bj[2][8];                              // resident j-row frags
    const int jrow = jgrp * 32 + lane;
    #pragma unroll
    for (int s = 0; s < 2; ++s) {
        const int jt = s ? jtB : jtA;
        #pragma unroll
        for (int kk = 0; kk < 8; ++kk)
            Bj[s][kk] = *(const f16x8*)&xtb[(((size_t)jt * 16 + 2 * kk + h) * 64 + jrow) * 8];
    }

    f32x16 aA0, aA1, aB0, aB1;                   // acc: [j-tile][c-half]
    #pragma unroll
    for (int r = 0; r < 16; ++r) { aA0[r] = 0.f; aA1[r] = 0.f; aB0[r] = 0.f; aB1[r] = 0.f; }

    const int arow = isub * 32 + lane;
    const int ptbase = (jgrp * 32 + lane) * PADV + isub * 32;
    const int pbrow = (jg * 32 + lane) * PADV + h * 8;

    // staging roles: waves 0,1 -> A halves; waves 2,3 -> V halves
    const bool wA = (w < 2);
    const int sh = (w & 1) * 4096;               // u16 offset of wave's 8 KB half

    {   // prologue stage: tile ti0 -> buf 0 (full drain once is fine)
        const u16* gs = (wA ? xtb + (size_t)ti0 * TSZA : xcb + (size_t)ti0 * TSZV)
                        + sh + l * 8;
        u16* ls = (wA ? &s_xa[0][0] : &s_xv[0][0]) + sh;
        #pragma unroll
        for (int k = 0; k < 8; ++k) gload_lds16(gs + k * 512, ls + k * 512);
    }
    __syncthreads();

    for (int ti = ti0; ti < ti1; ++ti) {
        const int cur = (ti - ti0) & 1;
        if (ti + 1 < ti1) {                      // stage next tile; stays in
            const u16* gs = (wA ? xtb + (size_t)(ti + 1) * TSZA          // flight
                                : xcb + (size_t)(ti + 1) * TSZV) + sh + l * 8;
            u16* ls = (wA ? &s_xa[cur ^ 1][0] : &s_xv[cur ^ 1][0]) + sh;
            #pragma unroll
            for (int k = 0; k < 8; ++k) gload_lds16(gs + k * 512, ls + k * 512);
        }
        const u16* sa = &s_xa[cur][0];
        const u16* sv = &s_xv[cur][0];
        const float* cbase = &row_c[b * Np + ti * 64 + isub * 32];

        #pragma unroll
        for (int s = 0; s < 2; ++s) {
            // energy: D[m=i32][n=j32], K=128; A-frags from LDS
            f32x16 ea;
            #pragma unroll
            for (int r = 0; r < 16; ++r) ea[r] = 0.f;
            __builtin_amdgcn_s_setprio(1);
            #pragma unroll
            for (int kk = 0; kk < 8; ++kk) {
                const f16x8 A = *(const f16x8*)&sa[((2 * kk + h) * 64 + arow) * 8];
                ea = __builtin_amdgcn_mfma_f32_32x32x16_f16(A, Bj[s][kk], ea, 0, 0, 0);
            }
            __builtin_amdgcn_s_setprio(0);

            // P = exp2(e*l2e - c_i) -> s_pt
            const bool dsub = (ti == (s ? jtB : jtA)) && (isub == jgrp);
            #pragma unroll
            for (int qq = 0; qq < 4; ++qq) {
                const f32x4 cv = *(const f32x4*)&cbase[qq * 8 + h * 4];
                f16x4 pv;
                #pragma unroll
                for (int r = 0; r < 4; ++r) {
                    const int m = qq * 8 + h * 4 + r;
                    float v = ea[qq * 4 + r];
                    if (dsub && m == lane) v = 0.f;
                    pv[r] = (_Float16)exp2fast(fmaf(v, L2E, -cv[r]));
                }
                *(f16x4*)&s_pt[ptbase + qq * 8 + h * 4] = pv;
            }
            W_LGKM(); BAR(); SCHED0();           // P visible; stage still in flight

            // PV: D[m=c][n=j]; V-frags + Bp from LDS
            __builtin_amdgcn_s_setprio(1);
            #pragma unroll
            for (int kk = 0; kk < 4; ++kk) {
                const f16x8 Bp  = *(const f16x8*)&s_pt[pbrow + kk * 16];
                const f16x8 Av0 = *(const f16x8*)&sv[((2 * kk + h) * 128 + cp * 64 + lane) * 8];
                const f16x8 Av1 = *(const f16x8*)&sv[((2 * kk + h) * 128 + cp * 64 + 32 + lane) * 8];
                if (s) {
                    aB0 = __builtin_amdgcn_mfma_f32_32x32x16_f16(Av0, Bp, aB0, 0, 0, 0);
                    aB1 = __builtin_amdgcn_mfma_f32_32x32x16_f16(Av1, Bp, aB1, 0, 0, 0);
                } else {
                    aA0 = __builtin_amdgcn_mfma_f32_32x32x16_f16(Av0, Bp, aA0, 0, 0, 0);
                    aA1 = __builtin_amdgcn_mfma_f32_32x32x16_f16(Av1, Bp, aA1, 0, 0, 0);
                }
            }
            __builtin_amdgcn_s_setprio(0);

            if (s == 0) { W_LGKM(); BAR(); SCHED0(); }   // P consumed -> reusable
        }

        // end of iter: drain stage (covered by 32 MFMA + 2 exp phases),
        // all reads of cur done -> buffers swappable.
        if (ti + 1 < ti1) { W_ALL(); } else { W_LGKM(); }
        BAR(); SCHED0();
    }

    // epilogue: raw f32 partials -> out slot q
    #pragma unroll
    for (int r = 0; r < 16; ++r) {
        const int mrow = (r & 3) + 8 * (r >> 2) + 4 * h;
        {
            const int jj = jtA * 64 + jg * 32 + lane;
            const size_t p0 = (size_t)(b * Cc + cp * 64 + mrow) * Nn + jj;
            const size_t p1 = (size_t)(b * Cc + cp * 64 + 32 + mrow) * Nn + jj;
            out[(size_t)q * Mm + p0] = aA0[r];
            out[(size_t)q * Mm + p1] = aA1[r];
        }
        if (jtB < 49) {
            const int jj = jtB * 64 + jg * 32 + lane;
            const size_t p0 = (size_t)(b * Cc + cp * 64 + mrow) * Nn + jj;
            const size_t p1 = (size_t)(b * Cc + cp * 64 + 32 + mrow) * Nn + jj;
            out[(size_t)q * Mm + p0] = aB0[r];
            out[(size_t)q * Mm + p1] = aB1[r];
        }
    }
}

// ---------------------------------------------------------------------------
// Finish: o = relu(p0+p1+p2); slot0 = gamma*o + x; slot1 = o; slot2 = x.
// ---------------------------------------------------------------------------
__global__ __launch_bounds__(256) void finish_kernel(const float* __restrict__ x,
                                                     const float* __restrict__ gamma_p,
                                                     float* __restrict__ out) {
    const float gamma = gamma_p[0];
    const size_t base = ((size_t)blockIdx.x * 256 + threadIdx.x) * 4;
    const f32x4 pa = *(const f32x4*)&out[base];
    const f32x4 pb = *(const f32x4*)&out[(size_t)Mm + base];
    const f32x4 pc = *(const f32x4*)&out[(size_t)2 * Mm + base];
    const f32x4 xv = *(const f32x4*)&x[base];
    f32x4 yo, oo;
    #pragma unroll
    for (int r = 0; r < 4; ++r) {
        const float o = fmaxf(pa[r] + pb[r] + pc[r], 0.0f);
        oo[r] = o;
        yo[r] = fmaf(gamma, o, xv[r]);
    }
    *(f32x4*)&out[base] = yo;
    *(f32x4*)&out[(size_t)Mm + base] = oo;
    *(f32x4*)&out[(size_t)2 * Mm + base] = xv;
}

extern "C" void kernel_launch(void* const* d_in, const int* in_sizes, int n_in,
                              void* d_out, int out_size, void* d_ws, size_t ws_size,
                              hipStream_t stream) {
    const float* x       = (const float*)d_in[0];
    const float* gamma_p = (const float*)d_in[1];
    float* out = (float*)d_out;

    // ws layout (~12.6 MB): row_d (8x3200 f32, 128K reserved) | xt2 | xc2
    float* row_d = (float*)d_ws;
    u16* xt2 = (u16*)((char*)d_ws + (1 << 17));
    u16* xc2 = xt2 + (size_t)Bb * XT2B;

    hipMemsetAsync(row_d, 0, (size_t)Bb * Np * sizeof(float), stream);
    prep_kernel  <<<400, 256, 0, stream>>>(x, gamma_p, out, xt2, xc2, row_d);
    stats_kernel <<<1600, 256, 0, stream>>>(xt2, row_d);
    conv_kernel  <<<100, 256, 0, stream>>>(row_d);
    out_kernel   <<<600, 256, 0, stream>>>(xt2, xc2, row_d, out);
    finish_kernel<<<3136, 256, 0, stream>>>(x, gamma_p, out);
}